// Round 5
// baseline (2611.075 us; speedup 1.0000x reference)
//
#include <hip/hip_runtime.h>
#include <cstdint>
#include <cstddef>

#define H 2048
#define F 5504
#define E 8
#define T 2048
#define ROWCAP 5120  // 4096 rows + 8*128 padding worst case

#define BM 128
#define BN 128
#define BK 32

typedef __bf16 bf16x8 __attribute__((ext_vector_type(8)));
typedef float f32x4 __attribute__((ext_vector_type(4)));

#define AS1(p) ((const __attribute__((address_space(1))) void*)(p))
#define AS3(p) ((__attribute__((address_space(3))) void*)(p))

// ---------------- router: fp32 logits, top-2, softmax, slot assignment ----------------
__global__ void router_kernel(const float* __restrict__ x,
                              const float* __restrict__ rw,
                              int* __restrict__ cnt,
                              int* __restrict__ list_t,
                              float* __restrict__ list_w) {
    const int wv = threadIdx.x >> 6;
    const int lane = threadIdx.x & 63;
    const int t = blockIdx.x * 4 + wv;
    const float4* xp = (const float4*)(x + (size_t)t * H) + lane * 8;
    float4 xv[8];
#pragma unroll
    for (int i = 0; i < 8; ++i) xv[i] = xp[i];
    float lg[E];
#pragma unroll
    for (int e = 0; e < E; ++e) {
        const float4* wp = (const float4*)(rw + (size_t)e * H) + lane * 8;
        float acc = 0.f;
#pragma unroll
        for (int i = 0; i < 8; ++i) {
            float4 w4 = wp[i];
            acc += xv[i].x * w4.x + xv[i].y * w4.y + xv[i].z * w4.z + xv[i].w * w4.w;
        }
#pragma unroll
        for (int o = 32; o > 0; o >>= 1) acc += __shfl_xor(acc, o, 64);
        lg[e] = acc;
    }
    if (lane == 0) {
        float v0 = -3e38f, v1 = -3e38f;
        int i0 = 0, i1 = 0;
#pragma unroll
        for (int e = 0; e < E; ++e) {
            float v = lg[e];
            if (v > v0) { v1 = v0; i1 = i0; v0 = v; i0 = e; }
            else if (v > v1) { v1 = v; i1 = e; }
        }
        float p0 = 1.f / (1.f + __expf(v1 - v0));
        float p1 = 1.f - p0;
        int s0 = atomicAdd(&cnt[i0], 1);
        list_t[i0 * T + s0] = t;
        list_w[i0 * T + s0] = p0;
        int s1 = atomicAdd(&cnt[i1], 1);
        list_t[i1 * T + s1] = t;
        list_w[i1 * T + s1] = p1;
    }
}

// ---------------- prefix: 128-aligned per-expert offsets ----------------
__global__ void offsets_kernel(const int* __restrict__ cnt, int* __restrict__ off) {
    if (threadIdx.x == 0) {
        int acc = 0;
        for (int e = 0; e < E; ++e) {
            off[e] = acc;
            acc += (cnt[e] + 127) & ~127;
        }
    }
}

// ---------------- gather: pack x rows (fp32 -> bf16) per expert ----------------
__global__ void gather_kernel(const float* __restrict__ x,
                              const int* __restrict__ cnt,
                              const int* __restrict__ off,
                              const int* __restrict__ list_t,
                              const float* __restrict__ list_w,
                              __bf16* __restrict__ Abuf,
                              int* __restrict__ row_t,
                              float* __restrict__ row_w) {
    const int e = blockIdx.y, slot = blockIdx.x;
    if (slot >= cnt[e]) return;
    const int row = off[e] + slot;
    if (threadIdx.x == 0) {
        row_t[row] = list_t[e * T + slot];
        row_w[row] = list_w[e * T + slot];
    }
    const int t = list_t[e * T + slot];
    const float4* src = (const float4*)(x + (size_t)t * H);
    float4 a = src[threadIdx.x * 2], b = src[threadIdx.x * 2 + 1];
    bf16x8 o;
    o[0] = (__bf16)a.x; o[1] = (__bf16)a.y; o[2] = (__bf16)a.z; o[3] = (__bf16)a.w;
    o[4] = (__bf16)b.x; o[5] = (__bf16)b.y; o[6] = (__bf16)b.z; o[7] = (__bf16)b.w;
    *(bf16x8*)(Abuf + (size_t)row * H + threadIdx.x * 8) = o;
}

// ---------------- weight pre-conversion: fp32 -> bf16, pure streaming ----------------
// Reads 1.08 GB, writes 0.54 GB; should run at HBM-achievable BW (~6 TB/s).
// Moves the bulk of weight bytes OUT of the latency-capped GEMM loops.
__global__ void convw_kernel(const float* __restrict__ s0, const float* __restrict__ s1,
                             const float* __restrict__ s2,
                             __bf16* __restrict__ d0, __bf16* __restrict__ d1,
                             __bf16* __restrict__ d2) {
    const float* s = blockIdx.y == 0 ? s0 : (blockIdx.y == 1 ? s1 : s2);
    __bf16* d = blockIdx.y == 0 ? d0 : (blockIdx.y == 1 ? d1 : d2);
    const size_t n = (size_t)E * F * H;
    size_t i = ((size_t)blockIdx.x * blockDim.x + threadIdx.x) * 8;
    const size_t stride = (size_t)gridDim.x * blockDim.x * 8;
    for (; i < n; i += stride) {
        float4 a = *(const float4*)(s + i);
        float4 b = *(const float4*)(s + i + 4);
        bf16x8 o;
        o[0] = (__bf16)a.x; o[1] = (__bf16)a.y; o[2] = (__bf16)a.z; o[3] = (__bf16)a.w;
        o[4] = (__bf16)b.x; o[5] = (__bf16)b.y; o[6] = (__bf16)b.z; o[7] = (__bf16)b.w;
        *(bf16x8*)(d + i) = o;
    }
}

// ---------------- gate+up GEMM (bf16 weights) + SwiGLU epilogue ----------------
// All staging via global_load_lds (A, G, U): no register staging, no in-loop cvt.
// Half the weight bytes vs fp32 path; (256,3) -> 3 blocks/CU for latency hiding.
// 2-phase double-buffer with statically-named LDS buffers.
__global__ void __launch_bounds__(256, 3)
gateup_bf16k(const __bf16* __restrict__ Abuf,
             const __bf16* __restrict__ gwb,
             const __bf16* __restrict__ uwb,
             const int* __restrict__ cnt,
             const int* __restrict__ off,
             const float* __restrict__ row_w,
             __bf16* __restrict__ act) {
    const int e = blockIdx.z;
    const int count = cnt[e];
    const int mt = blockIdx.y;
    if (mt * BM >= count) return;
    const int n0 = blockIdx.x * BN;
    const int rowbase = off[e] + mt * BM;

    __shared__ __bf16 As0[BM * BK], As1[BM * BK];
    __shared__ __bf16 Gs0[BN * BK], Gs1[BN * BK];
    __shared__ __bf16 Us0[BN * BK], Us1[BN * BK];  // 48KB total => 3 blocks/CU = 144KB

    const int tid = threadIdx.x;
    const int wv = tid >> 6, lane = tid & 63;
    const int wr = wv >> 1, wc = wv & 1;
    const int quad = lane >> 4, l16 = lane & 15;

    f32x4 accG[4][4] = {};
    f32x4 accU[4][4] = {};

    const __bf16* abase = Abuf + (size_t)rowbase * H;
    const __bf16* gbase = gwb + (size_t)e * F * H + (size_t)n0 * H;
    const __bf16* ubase = uwb + (size_t)e * F * H + (size_t)n0 * H;

    const int arow = lane >> 2;       // row within 16-row segment
    const int acol = (lane & 3) * 8;  // k-element offset (16B chunks)

#define STAGE(AS, GS, US, k0)                                                                \
    do {                                                                                     \
        _Pragma("unroll")                                                                    \
        for (int i_ = 0; i_ < 2; ++i_) {                                                     \
            const int seg_ = wv * 2 + i_;                                                    \
            const size_t roff_ = (size_t)(seg_ * 16 + arow);                                 \
            __builtin_amdgcn_global_load_lds(AS1(abase + roff_ * H + (k0) + acol),           \
                                             AS3(AS + seg_ * 512), 16, 0, 0);               \
            __builtin_amdgcn_global_load_lds(AS1(gbase + roff_ * H + (k0) + acol),           \
                                             AS3(GS + seg_ * 512), 16, 0, 0);               \
            __builtin_amdgcn_global_load_lds(AS1(ubase + roff_ * H + (k0) + acol),           \
                                             AS3(US + seg_ * 512), 16, 0, 0);               \
        }                                                                                    \
    } while (0)

#define COMPUTE(AS, GS, US)                                                                      \
    do {                                                                                         \
        bf16x8 af_[4], gf_[4], uf_[4];                                                           \
        _Pragma("unroll")                                                                        \
        for (int i_ = 0; i_ < 4; ++i_)                                                           \
            af_[i_] = *(const bf16x8*)(AS + (wr * 64 + i_ * 16 + l16) * BK + quad * 8);          \
        _Pragma("unroll")                                                                        \
        for (int j_ = 0; j_ < 4; ++j_) {                                                         \
            gf_[j_] = *(const bf16x8*)(GS + (wc * 64 + j_ * 16 + l16) * BK + quad * 8);          \
            uf_[j_] = *(const bf16x8*)(US + (wc * 64 + j_ * 16 + l16) * BK + quad * 8);          \
        }                                                                                        \
        _Pragma("unroll")                                                                        \
        for (int i_ = 0; i_ < 4; ++i_)                                                           \
            _Pragma("unroll")                                                                    \
            for (int j_ = 0; j_ < 4; ++j_) {                                                     \
                accG[i_][j_] = __builtin_amdgcn_mfma_f32_16x16x32_bf16(af_[i_], gf_[j_], accG[i_][j_], 0, 0, 0); \
                accU[i_][j_] = __builtin_amdgcn_mfma_f32_16x16x32_bf16(af_[i_], uf_[j_], accU[i_][j_], 0, 0, 0); \
            }                                                                                    \
    } while (0)

    STAGE(As0, Gs0, Us0, 0);
    __syncthreads();

    const int NT = H / BK;  // 64 (even)
    for (int t = 0; t < NT; t += 2) {
        STAGE(As1, Gs1, Us1, (t + 1) * BK);
        COMPUTE(As0, Gs0, Us0);
        __syncthreads();
        if (t + 2 < NT) STAGE(As0, Gs0, Us0, (t + 2) * BK);
        COMPUTE(As1, Gs1, Us1);
        __syncthreads();
    }

#undef STAGE
#undef COMPUTE

    // epilogue: act = silu(g) * u * combine_w
#pragma unroll
    for (int i = 0; i < 4; ++i) {
        const int ml = wr * 64 + i * 16 + quad * 4;
#pragma unroll
        for (int r = 0; r < 4; ++r) {
            const float w = row_w[rowbase + ml + r];
            __bf16* arow_p = act + (size_t)(rowbase + ml + r) * F + n0;
#pragma unroll
            for (int j = 0; j < 4; ++j) {
                const int nl = wc * 64 + j * 16 + l16;
                float g = accG[i][j][r], u = accU[i][j][r];
                float s = g / (1.f + __expf(-g));
                arow_p[nl] = (__bf16)(s * u * w);
            }
        }
    }
}

// ---------------- down GEMM (bf16 weights) + scatter-add ----------------
// (256,4): ~100 live regs fits the 128-reg budget; 4 blocks/CU, 32KB LDS x4 = 128KB.
__global__ void __launch_bounds__(256, 4)
down_bf16k(const __bf16* __restrict__ act,
           const __bf16* __restrict__ dwb,
           const int* __restrict__ cnt,
           const int* __restrict__ off,
           const int* __restrict__ row_t,
           float* __restrict__ out) {
    const int e = blockIdx.z;
    const int count = cnt[e];
    const int mt = blockIdx.y;
    if (mt * BM >= count) return;
    const int h0 = blockIdx.x * BN;
    const int rowbase = off[e] + mt * BM;

    __shared__ __bf16 As0[BM * BK], As1[BM * BK];
    __shared__ __bf16 Ws0[BN * BK], Ws1[BN * BK];  // 32KB

    const int tid = threadIdx.x;
    const int wv = tid >> 6, lane = tid & 63;
    const int wr = wv >> 1, wc = wv & 1;
    const int quad = lane >> 4, l16 = lane & 15;

    f32x4 acc[4][4] = {};

    const __bf16* abase = act + (size_t)rowbase * F;
    const __bf16* wbase = dwb + (size_t)e * H * F + (size_t)h0 * F;

    const int arow = lane >> 2;
    const int acol = (lane & 3) * 8;

#define STAGE(AS, WS, k0)                                                                    \
    do {                                                                                     \
        _Pragma("unroll")                                                                    \
        for (int i_ = 0; i_ < 2; ++i_) {                                                     \
            const int seg_ = wv * 2 + i_;                                                    \
            const size_t roff_ = (size_t)(seg_ * 16 + arow);                                 \
            __builtin_amdgcn_global_load_lds(AS1(abase + roff_ * F + (k0) + acol),           \
                                             AS3(AS + seg_ * 512), 16, 0, 0);               \
            __builtin_amdgcn_global_load_lds(AS1(wbase + roff_ * F + (k0) + acol),           \
                                             AS3(WS + seg_ * 512), 16, 0, 0);               \
        }                                                                                    \
    } while (0)

#define COMPUTE(AS, WS)                                                                          \
    do {                                                                                         \
        bf16x8 af_[4], bf_[4];                                                                   \
        _Pragma("unroll")                                                                        \
        for (int i_ = 0; i_ < 4; ++i_)                                                           \
            af_[i_] = *(const bf16x8*)(AS + (wr * 64 + i_ * 16 + l16) * BK + quad * 8);          \
        _Pragma("unroll")                                                                        \
        for (int j_ = 0; j_ < 4; ++j_)                                                           \
            bf_[j_] = *(const bf16x8*)(WS + (wc * 64 + j_ * 16 + l16) * BK + quad * 8);          \
        _Pragma("unroll")                                                                        \
        for (int i_ = 0; i_ < 4; ++i_)                                                           \
            _Pragma("unroll")                                                                    \
            for (int j_ = 0; j_ < 4; ++j_)                                                       \
                acc[i_][j_] = __builtin_amdgcn_mfma_f32_16x16x32_bf16(af_[i_], bf_[j_], acc[i_][j_], 0, 0, 0); \
    } while (0)

    STAGE(As0, Ws0, 0);
    __syncthreads();

    const int NT = F / BK;  // 172 (even)
    for (int t = 0; t < NT; t += 2) {
        STAGE(As1, Ws1, (t + 1) * BK);
        COMPUTE(As0, Ws0);
        __syncthreads();
        if (t + 2 < NT) STAGE(As0, Ws0, (t + 2) * BK);
        COMPUTE(As1, Ws1);
        __syncthreads();
    }

#undef STAGE
#undef COMPUTE

#pragma unroll
    for (int i = 0; i < 4; ++i) {
        const int ml = wr * 64 + i * 16 + quad * 4;
#pragma unroll
        for (int r = 0; r < 4; ++r) {
            const int lr = mt * BM + ml + r;
            if (lr < count) {
                const int t = row_t[rowbase + ml + r];
                float* orow = out + (size_t)t * H + h0;
#pragma unroll
                for (int j = 0; j < 4; ++j)
                    atomicAdd(&orow[wc * 64 + j * 16 + l16], acc[i][j][r]);
            }
        }
    }
}

// ================= FALLBACK PATH (fp32 weights in-loop, round-4 kernels) =================
__global__ void __launch_bounds__(256, 2)
gateup_f32k(const __bf16* __restrict__ Abuf,
            const float* __restrict__ gw,
            const float* __restrict__ uw,
            const int* __restrict__ cnt,
            const int* __restrict__ off,
            const float* __restrict__ row_w,
            __bf16* __restrict__ act) {
    const int e = blockIdx.z;
    const int count = cnt[e];
    const int mt = blockIdx.y;
    if (mt * BM >= count) return;
    const int n0 = blockIdx.x * BN;
    const int rowbase = off[e] + mt * BM;

    __shared__ __bf16 As0[BM * BK], As1[BM * BK];
    __shared__ __bf16 Gs0[BN * BK], Gs1[BN * BK];
    __shared__ __bf16 Us0[BN * BK], Us1[BN * BK];

    const int tid = threadIdx.x;
    const int wv = tid >> 6, lane = tid & 63;
    const int wr = wv >> 1, wc = wv & 1;
    const int quad = lane >> 4, l16 = lane & 15;

    f32x4 accG[4][4] = {};
    f32x4 accU[4][4] = {};

    const __bf16* abase = Abuf + (size_t)rowbase * H;
    const float* gbase = gw + (size_t)e * F * H + (size_t)n0 * H;
    const float* ubase = uw + (size_t)e * F * H + (size_t)n0 * H;

    const int arow = lane >> 2;
    const int acol = (lane & 3) * 8;
    const int wrow = tid >> 1;
    const int kh = (tid & 1) * 16;

    float4 pg[4], pu[4];

#define STAGE_A(AS, k0)                                                                  \
    do {                                                                                 \
        _Pragma("unroll")                                                                \
        for (int i_ = 0; i_ < 2; ++i_) {                                                 \
            const int seg_ = wv * 2 + i_;                                                \
            const __bf16* gp_ = abase + (size_t)(seg_ * 16 + arow) * H + (k0) + acol;    \
            __builtin_amdgcn_global_load_lds(AS1(gp_), AS3(AS + seg_ * 512), 16, 0, 0);  \
        }                                                                                \
    } while (0)

#define LOAD_W(k0)                                                                   \
    do {                                                                             \
        const float4* gp_ = (const float4*)(gbase + (size_t)wrow * H + (k0) + kh);   \
        pg[0] = gp_[0]; pg[1] = gp_[1]; pg[2] = gp_[2]; pg[3] = gp_[3];              \
        const float4* up_ = (const float4*)(ubase + (size_t)wrow * H + (k0) + kh);   \
        pu[0] = up_[0]; pu[1] = up_[1]; pu[2] = up_[2]; pu[3] = up_[3];              \
    } while (0)

#define WRITE_W(GS, US)                                                                          \
    do {                                                                                         \
        bf16x8 h0_, h1_;                                                                         \
        h0_[0] = (__bf16)pg[0].x; h0_[1] = (__bf16)pg[0].y; h0_[2] = (__bf16)pg[0].z; h0_[3] = (__bf16)pg[0].w; \
        h0_[4] = (__bf16)pg[1].x; h0_[5] = (__bf16)pg[1].y; h0_[6] = (__bf16)pg[1].z; h0_[7] = (__bf16)pg[1].w; \
        h1_[0] = (__bf16)pg[2].x; h1_[1] = (__bf16)pg[2].y; h1_[2] = (__bf16)pg[2].z; h1_[3] = (__bf16)pg[2].w; \
        h1_[4] = (__bf16)pg[3].x; h1_[5] = (__bf16)pg[3].y; h1_[6] = (__bf16)pg[3].z; h1_[7] = (__bf16)pg[3].w; \
        *(bf16x8*)(GS + wrow * BK + kh) = h0_;                                                   \
        *(bf16x8*)(GS + wrow * BK + kh + 8) = h1_;                                               \
        h0_[0] = (__bf16)pu[0].x; h0_[1] = (__bf16)pu[0].y; h0_[2] = (__bf16)pu[0].z; h0_[3] = (__bf16)pu[0].w; \
        h0_[4] = (__bf16)pu[1].x; h0_[5] = (__bf16)pu[1].y; h0_[6] = (__bf16)pu[1].z; h0_[7] = (__bf16)pu[1].w; \
        h1_[0] = (__bf16)pu[2].x; h1_[1] = (__bf16)pu[2].y; h1_[2] = (__bf16)pu[2].z; h1_[3] = (__bf16)pu[2].w; \
        h1_[4] = (__bf16)pu[3].x; h1_[5] = (__bf16)pu[3].y; h1_[6] = (__bf16)pu[3].z; h1_[7] = (__bf16)pu[3].w; \
        *(bf16x8*)(US + wrow * BK + kh) = h0_;                                                   \
        *(bf16x8*)(US + wrow * BK + kh + 8) = h1_;                                               \
    } while (0)

#define COMPUTE(AS, GS, US)                                                                      \
    do {                                                                                         \
        bf16x8 af_[4], gf_[4], uf_[4];                                                           \
        _Pragma("unroll")                                                                        \
        for (int i_ = 0; i_ < 4; ++i_)                                                           \
            af_[i_] = *(const bf16x8*)(AS + (wr * 64 + i_ * 16 + l16) * BK + quad * 8);          \
        _Pragma("unroll")                                                                        \
        for (int j_ = 0; j_ < 4; ++j_) {                                                         \
            gf_[j_] = *(const bf16x8*)(GS + (wc * 64 + j_ * 16 + l16) * BK + quad * 8);          \
            uf_[j_] = *(const bf16x8*)(US + (wc * 64 + j_ * 16 + l16) * BK + quad * 8);          \
        }                                                                                        \
        _Pragma("unroll")                                                                        \
        for (int i_ = 0; i_ < 4; ++i_)                                                           \
            _Pragma("unroll")                                                                    \
            for (int j_ = 0; j_ < 4; ++j_) {                                                     \
                accG[i_][j_] = __builtin_amdgcn_mfma_f32_16x16x32_bf16(af_[i_], gf_[j_], accG[i_][j_], 0, 0, 0); \
                accU[i_][j_] = __builtin_amdgcn_mfma_f32_16x16x32_bf16(af_[i_], uf_[j_], accU[i_][j_], 0, 0, 0); \
            }                                                                                    \
    } while (0)

    STAGE_A(As0, 0);
    LOAD_W(0);
    WRITE_W(Gs0, Us0);
    __syncthreads();

    const int NT = H / BK;
    for (int t = 0; t < NT; t += 2) {
        STAGE_A(As1, (t + 1) * BK);
        LOAD_W((t + 1) * BK);
        COMPUTE(As0, Gs0, Us0);
        WRITE_W(Gs1, Us1);
        __syncthreads();
        if (t + 2 < NT) {
            STAGE_A(As0, (t + 2) * BK);
            LOAD_W((t + 2) * BK);
        }
        COMPUTE(As1, Gs1, Us1);
        if (t + 2 < NT) WRITE_W(Gs0, Us0);
        __syncthreads();
    }

#undef STAGE_A
#undef LOAD_W
#undef WRITE_W
#undef COMPUTE

#pragma unroll
    for (int i = 0; i < 4; ++i) {
        const int ml = wr * 64 + i * 16 + quad * 4;
#pragma unroll
        for (int r = 0; r < 4; ++r) {
            const float w = row_w[rowbase + ml + r];
            __bf16* arow_p = act + (size_t)(rowbase + ml + r) * F + n0;
#pragma unroll
            for (int j = 0; j < 4; ++j) {
                const int nl = wc * 64 + j * 16 + l16;
                float g = accG[i][j][r], u = accU[i][j][r];
                float s = g / (1.f + __expf(-g));
                arow_p[nl] = (__bf16)(s * u * w);
            }
        }
    }
}

__global__ void __launch_bounds__(256, 2)
down_f32k(const __bf16* __restrict__ act,
          const float* __restrict__ dw,
          const int* __restrict__ cnt,
          const int* __restrict__ off,
          const int* __restrict__ row_t,
          float* __restrict__ out) {
    const int e = blockIdx.z;
    const int count = cnt[e];
    const int mt = blockIdx.y;
    if (mt * BM >= count) return;
    const int h0 = blockIdx.x * BN;
    const int rowbase = off[e] + mt * BM;

    __shared__ __bf16 As0[BM * BK], As1[BM * BK];
    __shared__ __bf16 Ws0[BN * BK], Ws1[BN * BK];

    const int tid = threadIdx.x;
    const int wv = tid >> 6, lane = tid & 63;
    const int wr = wv >> 1, wc = wv & 1;
    const int quad = lane >> 4, l16 = lane & 15;

    f32x4 acc[4][4] = {};

    const __bf16* abase = act + (size_t)rowbase * F;
    const float* wbase = dw + (size_t)e * H * F + (size_t)h0 * F;

    const int arow = lane >> 2;
    const int acol = (lane & 3) * 8;
    const int wrow = tid >> 1;
    const int kh = (tid & 1) * 16;

    float4 pw[4];

#define STAGE_A(AS, k0)                                                                  \
    do {                                                                                 \
        _Pragma("unroll")                                                                \
        for (int i_ = 0; i_ < 2; ++i_) {                                                 \
            const int seg_ = wv * 2 + i_;                                                \
            const __bf16* gp_ = abase + (size_t)(seg_ * 16 + arow) * F + (k0) + acol;    \
            __builtin_amdgcn_global_load_lds(AS1(gp_), AS3(AS + seg_ * 512), 16, 0, 0);  \
        }                                                                                \
    } while (0)

#define LOAD_W(k0)                                                                   \
    do {                                                                             \
        const float4* gp_ = (const float4*)(wbase + (size_t)wrow * F + (k0) + kh);   \
        pw[0] = gp_[0]; pw[1] = gp_[1]; pw[2] = gp_[2]; pw[3] = gp_[3];              \
    } while (0)

#define WRITE_W(WS)                                                                              \
    do {                                                                                         \
        bf16x8 h0_, h1_;                                                                         \
        h0_[0] = (__bf16)pw[0].x; h0_[1] = (__bf16)pw[0].y; h0_[2] = (__bf16)pw[0].z; h0_[3] = (__bf16)pw[0].w; \
        h0_[4] = (__bf16)pw[1].x; h0_[5] = (__bf16)pw[1].y; h0_[6] = (__bf16)pw[1].z; h0_[7] = (__bf16)pw[1].w; \
        h1_[0] = (__bf16)pw[2].x; h1_[1] = (__bf16)pw[2].y; h1_[2] = (__bf16)pw[2].z; h1_[3] = (__bf16)pw[2].w; \
        h1_[4] = (__bf16)pw[3].x; h1_[5] = (__bf16)pw[3].y; h1_[6] = (__bf16)pw[3].z; h1_[7] = (__bf16)pw[3].w; \
        *(bf16x8*)(WS + wrow * BK + kh) = h0_;                                                   \
        *(bf16x8*)(WS + wrow * BK + kh + 8) = h1_;                                               \
    } while (0)

#define COMPUTE(AS, WS)                                                                          \
    do {                                                                                         \
        bf16x8 af_[4], bf_[4];                                                                   \
        _Pragma("unroll")                                                                        \
        for (int i_ = 0; i_ < 4; ++i_)                                                           \
            af_[i_] = *(const bf16x8*)(AS + (wr * 64 + i_ * 16 + l16) * BK + quad * 8);          \
        _Pragma("unroll")                                                                        \
        for (int j_ = 0; j_ < 4; ++j_)                                                           \
            bf_[j_] = *(const bf16x8*)(WS + (wc * 64 + j_ * 16 + l16) * BK + quad * 8);          \
        _Pragma("unroll")                                                                        \
        for (int i_ = 0; i_ < 4; ++i_)                                                           \
            _Pragma("unroll")                                                                    \
            for (int j_ = 0; j_ < 4; ++j_)                                                       \
                acc[i_][j_] = __builtin_amdgcn_mfma_f32_16x16x32_bf16(af_[i_], bf_[j_], acc[i_][j_], 0, 0, 0); \
    } while (0)

    STAGE_A(As0, 0);
    LOAD_W(0);
    WRITE_W(Ws0);
    __syncthreads();

    const int NT = F / BK;
    for (int t = 0; t < NT; t += 2) {
        STAGE_A(As1, (t + 1) * BK);
        LOAD_W((t + 1) * BK);
        COMPUTE(As0, Ws0);
        WRITE_W(Ws1);
        __syncthreads();
        if (t + 2 < NT) {
            STAGE_A(As0, (t + 2) * BK);
            LOAD_W((t + 2) * BK);
        }
        COMPUTE(As1, Ws1);
        if (t + 2 < NT) WRITE_W(Ws0);
        __syncthreads();
    }

#undef STAGE_A
#undef LOAD_W
#undef WRITE_W
#undef COMPUTE

#pragma unroll
    for (int i = 0; i < 4; ++i) {
        const int ml = wr * 64 + i * 16 + quad * 4;
#pragma unroll
        for (int r = 0; r < 4; ++r) {
            const int lr = mt * BM + ml + r;
            if (lr < count) {
                const int t = row_t[rowbase + ml + r];
                float* orow = out + (size_t)t * H + h0;
#pragma unroll
                for (int j = 0; j < 4; ++j)
                    atomicAdd(&orow[wc * 64 + j * 16 + l16], acc[i][j][r]);
            }
        }
    }
}

extern "C" void kernel_launch(void* const* d_in, const int* in_sizes, int n_in,
                              void* d_out, int out_size, void* d_ws, size_t ws_size,
                              hipStream_t stream) {
    const float* x  = (const float*)d_in[0];
    const float* rw = (const float*)d_in[1];
    const float* gw = (const float*)d_in[2];
    const float* uw = (const float*)d_in[3];
    const float* dw = (const float*)d_in[4];
    float* out = (float*)d_out;
    char* ws = (char*)d_ws;

    int*   cnt    = (int*)(ws + 0);
    int*   off    = (int*)(ws + 256);
    int*   list_t = (int*)(ws + 1024);
    float* list_w = (float*)(ws + 1024 + 65536);
    int*   row_t  = (int*)(ws + 1024 + 2 * 65536);
    float* row_w  = (float*)(ws + 1024 + 2 * 65536 + ROWCAP * 4);

    const size_t ABUF_OFF = 262144;
    const size_t ACT_OFF  = ABUF_OFF + (size_t)ROWCAP * H * 2;   // 21,233,664
    const size_t WGB_OFF  = ACT_OFF + (size_t)ROWCAP * F * 2;    // 77,594,624
    const size_t WSZ      = (size_t)E * F * H * 2;               // 180,355,072
    const size_t NEED     = WGB_OFF + 3 * WSZ;                   // 618,659,840

    __bf16* Abuf = (__bf16*)(ws + ABUF_OFF);
    __bf16* act  = (__bf16*)(ws + ACT_OFF);

    hipMemsetAsync(d_out, 0, (size_t)out_size * sizeof(float), stream);
    hipMemsetAsync(ws, 0, 1024, stream);

    router_kernel<<<T / 4, 256, 0, stream>>>(x, rw, cnt, list_t, list_w);
    offsets_kernel<<<1, 64, 0, stream>>>(cnt, off);
    gather_kernel<<<dim3(T, E), 256, 0, stream>>>(x, cnt, off, list_t, list_w, Abuf, row_t, row_w);

    if (ws_size >= NEED) {
        __bf16* wgb = (__bf16*)(ws + WGB_OFF);
        __bf16* wub = (__bf16*)(ws + WGB_OFF + WSZ);
        __bf16* wdb = (__bf16*)(ws + WGB_OFF + 2 * WSZ);
        convw_kernel<<<dim3(2048, 3), 256, 0, stream>>>(gw, uw, dw, wgb, wub, wdb);
        gateup_bf16k<<<dim3(F / BN, T / BM, E), 256, 0, stream>>>(Abuf, wgb, wub, cnt, off, row_w, act);
        down_bf16k<<<dim3(H / BN, T / BM, E), 256, 0, stream>>>(act, wdb, cnt, off, row_t, out);
    } else {
        gateup_f32k<<<dim3(F / BN, T / BM, E), 256, 0, stream>>>(Abuf, gw, uw, cnt, off, row_w, act);
        down_f32k<<<dim3(H / BN, T / BM, E), 256, 0, stream>>>(act, dw, cnt, off, row_t, out);
    }
}

// Round 6
// 1599.205 us; speedup vs baseline: 1.6327x; 1.6327x over previous
//
#include <hip/hip_runtime.h>
#include <cstdint>
#include <cstddef>

#define H 2048
#define F 5504
#define E 8
#define T 2048
#define ROWCAP 5120  // 4096 rows + 8*128 padding worst case

#define BM 128
#define BN 128
#define BK 32
#define DBK 64  // down-kernel K-step

// NOTE (round-5 lesson): do NOT pre-convert weights into workspace — 541 MB of
// same-launch dirty workspace lines thrash L2/L3 (measured: FETCH 1.74->2.94 GB,
// WRITE 0.05->2.18 GB, 533->1383 us). fp32 weights converted in-loop is faster.

typedef __bf16 bf16x8 __attribute__((ext_vector_type(8)));
typedef float f32x4 __attribute__((ext_vector_type(4)));

#define AS1(p) ((const __attribute__((address_space(1))) void*)(p))
#define AS3(p) ((__attribute__((address_space(3))) void*)(p))

// ---------------- router: fp32 logits, top-2, softmax, slot assignment ----------------
__global__ void router_kernel(const float* __restrict__ x,
                              const float* __restrict__ rw,
                              int* __restrict__ cnt,
                              int* __restrict__ list_t,
                              float* __restrict__ list_w) {
    const int wv = threadIdx.x >> 6;
    const int lane = threadIdx.x & 63;
    const int t = blockIdx.x * 4 + wv;
    const float4* xp = (const float4*)(x + (size_t)t * H) + lane * 8;
    float4 xv[8];
#pragma unroll
    for (int i = 0; i < 8; ++i) xv[i] = xp[i];
    float lg[E];
#pragma unroll
    for (int e = 0; e < E; ++e) {
        const float4* wp = (const float4*)(rw + (size_t)e * H) + lane * 8;
        float acc = 0.f;
#pragma unroll
        for (int i = 0; i < 8; ++i) {
            float4 w4 = wp[i];
            acc += xv[i].x * w4.x + xv[i].y * w4.y + xv[i].z * w4.z + xv[i].w * w4.w;
        }
#pragma unroll
        for (int o = 32; o > 0; o >>= 1) acc += __shfl_xor(acc, o, 64);
        lg[e] = acc;
    }
    if (lane == 0) {
        float v0 = -3e38f, v1 = -3e38f;
        int i0 = 0, i1 = 0;
#pragma unroll
        for (int e = 0; e < E; ++e) {
            float v = lg[e];
            if (v > v0) { v1 = v0; i1 = i0; v0 = v; i0 = e; }
            else if (v > v1) { v1 = v; i1 = e; }
        }
        float p0 = 1.f / (1.f + __expf(v1 - v0));
        float p1 = 1.f - p0;
        int s0 = atomicAdd(&cnt[i0], 1);
        list_t[i0 * T + s0] = t;
        list_w[i0 * T + s0] = p0;
        int s1 = atomicAdd(&cnt[i1], 1);
        list_t[i1 * T + s1] = t;
        list_w[i1 * T + s1] = p1;
    }
}

// ---------------- prefix: 128-aligned per-expert offsets ----------------
__global__ void offsets_kernel(const int* __restrict__ cnt, int* __restrict__ off) {
    if (threadIdx.x == 0) {
        int acc = 0;
        for (int e = 0; e < E; ++e) {
            off[e] = acc;
            acc += (cnt[e] + 127) & ~127;
        }
    }
}

// ---------------- gather: pack x rows (fp32 -> bf16) per expert ----------------
__global__ void gather_kernel(const float* __restrict__ x,
                              const int* __restrict__ cnt,
                              const int* __restrict__ off,
                              const int* __restrict__ list_t,
                              const float* __restrict__ list_w,
                              __bf16* __restrict__ Abuf,
                              int* __restrict__ row_t,
                              float* __restrict__ row_w) {
    const int e = blockIdx.y, slot = blockIdx.x;
    if (slot >= cnt[e]) return;
    const int row = off[e] + slot;
    if (threadIdx.x == 0) {
        row_t[row] = list_t[e * T + slot];
        row_w[row] = list_w[e * T + slot];
    }
    const int t = list_t[e * T + slot];
    const float4* src = (const float4*)(x + (size_t)t * H);
    float4 a = src[threadIdx.x * 2], b = src[threadIdx.x * 2 + 1];
    bf16x8 o;
    o[0] = (__bf16)a.x; o[1] = (__bf16)a.y; o[2] = (__bf16)a.z; o[3] = (__bf16)a.w;
    o[4] = (__bf16)b.x; o[5] = (__bf16)b.y; o[6] = (__bf16)b.z; o[7] = (__bf16)b.w;
    *(bf16x8*)(Abuf + (size_t)row * H + threadIdx.x * 8) = o;
}

// ---------------- fused gate+up GEMM + SwiGLU epilogue (round-4 proven, 533 us) ----------
__global__ void __launch_bounds__(256, 2)
gateup_kernel(const __bf16* __restrict__ Abuf,
              const float* __restrict__ gw,
              const float* __restrict__ uw,
              const int* __restrict__ cnt,
              const int* __restrict__ off,
              const float* __restrict__ row_w,
              __bf16* __restrict__ act) {
    const int e = blockIdx.z;
    const int count = cnt[e];
    const int mt = blockIdx.y;
    if (mt * BM >= count) return;
    const int n0 = blockIdx.x * BN;
    const int rowbase = off[e] + mt * BM;

    __shared__ __bf16 As0[BM * BK], As1[BM * BK];
    __shared__ __bf16 Gs0[BN * BK], Gs1[BN * BK];
    __shared__ __bf16 Us0[BN * BK], Us1[BN * BK];  // 48KB

    const int tid = threadIdx.x;
    const int wv = tid >> 6, lane = tid & 63;
    const int wr = wv >> 1, wc = wv & 1;
    const int quad = lane >> 4, l16 = lane & 15;

    f32x4 accG[4][4] = {};
    f32x4 accU[4][4] = {};

    const __bf16* abase = Abuf + (size_t)rowbase * H;
    const float* gbase = gw + (size_t)e * F * H + (size_t)n0 * H;
    const float* ubase = uw + (size_t)e * F * H + (size_t)n0 * H;

    const int arow = lane >> 2;
    const int acol = (lane & 3) * 8;
    const int wrow = tid >> 1;
    const int kh = (tid & 1) * 16;

    float4 pg[4], pu[4];

#define STAGE_A(AS, k0)                                                                  \
    do {                                                                                 \
        _Pragma("unroll")                                                                \
        for (int i_ = 0; i_ < 2; ++i_) {                                                 \
            const int seg_ = wv * 2 + i_;                                                \
            const __bf16* gp_ = abase + (size_t)(seg_ * 16 + arow) * H + (k0) + acol;    \
            __builtin_amdgcn_global_load_lds(AS1(gp_), AS3(AS + seg_ * 512), 16, 0, 0);  \
        }                                                                                \
    } while (0)

#define LOAD_W(k0)                                                                   \
    do {                                                                             \
        const float4* gp_ = (const float4*)(gbase + (size_t)wrow * H + (k0) + kh);   \
        pg[0] = gp_[0]; pg[1] = gp_[1]; pg[2] = gp_[2]; pg[3] = gp_[3];              \
        const float4* up_ = (const float4*)(ubase + (size_t)wrow * H + (k0) + kh);   \
        pu[0] = up_[0]; pu[1] = up_[1]; pu[2] = up_[2]; pu[3] = up_[3];              \
    } while (0)

#define WRITE_W(GS, US)                                                                          \
    do {                                                                                         \
        bf16x8 h0_, h1_;                                                                         \
        h0_[0] = (__bf16)pg[0].x; h0_[1] = (__bf16)pg[0].y; h0_[2] = (__bf16)pg[0].z; h0_[3] = (__bf16)pg[0].w; \
        h0_[4] = (__bf16)pg[1].x; h0_[5] = (__bf16)pg[1].y; h0_[6] = (__bf16)pg[1].z; h0_[7] = (__bf16)pg[1].w; \
        h1_[0] = (__bf16)pg[2].x; h1_[1] = (__bf16)pg[2].y; h1_[2] = (__bf16)pg[2].z; h1_[3] = (__bf16)pg[2].w; \
        h1_[4] = (__bf16)pg[3].x; h1_[5] = (__bf16)pg[3].y; h1_[6] = (__bf16)pg[3].z; h1_[7] = (__bf16)pg[3].w; \
        *(bf16x8*)(GS + wrow * BK + kh) = h0_;                                                   \
        *(bf16x8*)(GS + wrow * BK + kh + 8) = h1_;                                               \
        h0_[0] = (__bf16)pu[0].x; h0_[1] = (__bf16)pu[0].y; h0_[2] = (__bf16)pu[0].z; h0_[3] = (__bf16)pu[0].w; \
        h0_[4] = (__bf16)pu[1].x; h0_[5] = (__bf16)pu[1].y; h0_[6] = (__bf16)pu[1].z; h0_[7] = (__bf16)pu[1].w; \
        h1_[0] = (__bf16)pu[2].x; h1_[1] = (__bf16)pu[2].y; h1_[2] = (__bf16)pu[2].z; h1_[3] = (__bf16)pu[2].w; \
        h1_[4] = (__bf16)pu[3].x; h1_[5] = (__bf16)pu[3].y; h1_[6] = (__bf16)pu[3].z; h1_[7] = (__bf16)pu[3].w; \
        *(bf16x8*)(US + wrow * BK + kh) = h0_;                                                   \
        *(bf16x8*)(US + wrow * BK + kh + 8) = h1_;                                               \
    } while (0)

#define COMPUTE(AS, GS, US)                                                                      \
    do {                                                                                         \
        bf16x8 af_[4], gf_[4], uf_[4];                                                           \
        _Pragma("unroll")                                                                        \
        for (int i_ = 0; i_ < 4; ++i_)                                                           \
            af_[i_] = *(const bf16x8*)(AS + (wr * 64 + i_ * 16 + l16) * BK + quad * 8);          \
        _Pragma("unroll")                                                                        \
        for (int j_ = 0; j_ < 4; ++j_) {                                                         \
            gf_[j_] = *(const bf16x8*)(GS + (wc * 64 + j_ * 16 + l16) * BK + quad * 8);          \
            uf_[j_] = *(const bf16x8*)(US + (wc * 64 + j_ * 16 + l16) * BK + quad * 8);          \
        }                                                                                        \
        _Pragma("unroll")                                                                        \
        for (int i_ = 0; i_ < 4; ++i_)                                                           \
            _Pragma("unroll")                                                                    \
            for (int j_ = 0; j_ < 4; ++j_) {                                                     \
                accG[i_][j_] = __builtin_amdgcn_mfma_f32_16x16x32_bf16(af_[i_], gf_[j_], accG[i_][j_], 0, 0, 0); \
                accU[i_][j_] = __builtin_amdgcn_mfma_f32_16x16x32_bf16(af_[i_], uf_[j_], accU[i_][j_], 0, 0, 0); \
            }                                                                                    \
    } while (0)

    STAGE_A(As0, 0);
    LOAD_W(0);
    WRITE_W(Gs0, Us0);
    __syncthreads();

    const int NT = H / BK;  // 64 (even)
    for (int t = 0; t < NT; t += 2) {
        STAGE_A(As1, (t + 1) * BK);
        LOAD_W((t + 1) * BK);
        COMPUTE(As0, Gs0, Us0);
        WRITE_W(Gs1, Us1);
        __syncthreads();
        if (t + 2 < NT) {
            STAGE_A(As0, (t + 2) * BK);
            LOAD_W((t + 2) * BK);
        }
        COMPUTE(As1, Gs1, Us1);
        if (t + 2 < NT) WRITE_W(Gs0, Us0);
        __syncthreads();
    }

#undef STAGE_A
#undef LOAD_W
#undef WRITE_W
#undef COMPUTE

#pragma unroll
    for (int i = 0; i < 4; ++i) {
        const int ml = wr * 64 + i * 16 + quad * 4;
#pragma unroll
        for (int r = 0; r < 4; ++r) {
            const float w = row_w[rowbase + ml + r];
            __bf16* arow_p = act + (size_t)(rowbase + ml + r) * F + n0;
#pragma unroll
            for (int j = 0; j < 4; ++j) {
                const int nl = wc * 64 + j * 16 + l16;
                float g = accG[i][j][r], u = accU[i][j][r];
                float s = g / (1.f + __expf(-g));
                arow_p[nl] = (__bf16)(s * u * w);
            }
        }
    }
}

// ---------------- down GEMM + scatter-add: BK=64, split-K=2, XOR-swizzled LDS ----------
// Round-4 down (BK=32, 172 steps) inferred ~1000us at <0.5 TB/s: latency-bound on
// per-step barrier drains. This version: 43 steps/block (DBK=64, F split in 2 via
// atomicAdd merge), 1088 active blocks, and T2 swizzle (16-way -> 2-way LDS reads).
// Swizzle (rule #21): A via global_load_lds with PRE-SWIZZLED global source;
// W via swizzled ds_write; both read back with slot ^= (row&7).
__global__ void __launch_bounds__(256, 2)
down_kernel(const __bf16* __restrict__ act,
            const float* __restrict__ dw,
            const int* __restrict__ cnt,
            const int* __restrict__ off,
            const int* __restrict__ row_t,
            float* __restrict__ out) {
    const int e = blockIdx.z;
    const int count = cnt[e];
    const int mt = blockIdx.y;
    if (mt * BM >= count) return;
    const int h0 = (blockIdx.x & 15) * BN;
    const int ksl = blockIdx.x >> 4;       // split-K slice 0/1
    const int kbase = ksl * (F / 2);       // 0 or 2752 (= 43*64)
    const int rowbase = off[e] + mt * BM;

    __shared__ __bf16 As0[BM * DBK], As1[BM * DBK];  // 16KB each
    __shared__ __bf16 Ws0[BN * DBK], Ws1[BN * DBK];  // 16KB each => 64KB

    const int tid = threadIdx.x;
    const int wv = tid >> 6, lane = tid & 63;
    const int wr = wv >> 1, wc = wv & 1;
    const int quad = lane >> 4, l16 = lane & 15;

    f32x4 acc[4][4] = {};

    const __bf16* abase = act + (size_t)rowbase * F;
    const float* wbase = dw + (size_t)e * H * F + (size_t)h0 * F;

    // A staging: [128][64] bf16, 8 lanes/row, source col-slot pre-swizzled so the
    // linear global_load_lds write lands swizzled: slot_stored = (lane&7), data from
    // global slot (lane&7)^(row&7). row&7 == lane>>3 since segs are 8-row aligned.
    const int arow8 = lane >> 3;                       // row within 8-row seg = row&7
    const int ascol = ((lane & 7) ^ arow8) * 8;        // pre-swizzled source elem offset
    // W staging: 2 threads/row, 32 floats each
    const int wrow = tid >> 1;
    const int kh = (tid & 1) * 32;                     // float offset (slot base (tid&1)*4)

    float4 pw[8];

#define DSTAGE_A(AS, k0)                                                                 \
    do {                                                                                 \
        _Pragma("unroll")                                                                \
        for (int i_ = 0; i_ < 4; ++i_) {                                                 \
            const int seg_ = wv * 4 + i_;                                                \
            const __bf16* gp_ = abase + (size_t)(seg_ * 8 + arow8) * F + (k0) + ascol;   \
            __builtin_amdgcn_global_load_lds(AS1(gp_), AS3(AS + seg_ * 512), 16, 0, 0);  \
        }                                                                                \
    } while (0)

#define DLOAD_W(k0)                                                                  \
    do {                                                                             \
        const float4* gp_ = (const float4*)(wbase + (size_t)wrow * F + (k0) + kh);   \
        _Pragma("unroll")                                                            \
        for (int j_ = 0; j_ < 8; ++j_) pw[j_] = gp_[j_];                             \
    } while (0)

#define DWRITE_W(WS)                                                                             \
    do {                                                                                         \
        _Pragma("unroll")                                                                        \
        for (int j8_ = 0; j8_ < 4; ++j8_) {                                                      \
            float4 a_ = pw[2 * j8_], b_ = pw[2 * j8_ + 1];                                       \
            bf16x8 h_;                                                                           \
            h_[0] = (__bf16)a_.x; h_[1] = (__bf16)a_.y; h_[2] = (__bf16)a_.z; h_[3] = (__bf16)a_.w; \
            h_[4] = (__bf16)b_.x; h_[5] = (__bf16)b_.y; h_[6] = (__bf16)b_.z; h_[7] = (__bf16)b_.w; \
            const int slot_ = ((tid & 1) * 4 + j8_) ^ (wrow & 7);                                \
            *(bf16x8*)(WS + wrow * DBK + slot_ * 8) = h_;                                        \
        }                                                                                        \
    } while (0)

#define DCOMPUTE(AS, WS)                                                                         \
    do {                                                                                         \
        _Pragma("unroll")                                                                        \
        for (int ks2_ = 0; ks2_ < 2; ++ks2_) {                                                   \
            bf16x8 af_[4], bf_[4];                                                               \
            _Pragma("unroll")                                                                    \
            for (int i_ = 0; i_ < 4; ++i_) {                                                     \
                const int r_ = wr * 64 + i_ * 16 + l16;                                          \
                af_[i_] = *(const bf16x8*)(AS + r_ * DBK + ((ks2_ * 4 + quad) ^ (r_ & 7)) * 8);  \
            }                                                                                    \
            _Pragma("unroll")                                                                    \
            for (int j_ = 0; j_ < 4; ++j_) {                                                     \
                const int r_ = wc * 64 + j_ * 16 + l16;                                          \
                bf_[j_] = *(const bf16x8*)(WS + r_ * DBK + ((ks2_ * 4 + quad) ^ (r_ & 7)) * 8);  \
            }                                                                                    \
            _Pragma("unroll")                                                                    \
            for (int i_ = 0; i_ < 4; ++i_)                                                       \
                _Pragma("unroll")                                                                \
                for (int j_ = 0; j_ < 4; ++j_)                                                   \
                    acc[i_][j_] = __builtin_amdgcn_mfma_f32_16x16x32_bf16(af_[i_], bf_[j_], acc[i_][j_], 0, 0, 0); \
        }                                                                                        \
    } while (0)

    DSTAGE_A(As0, kbase);
    DLOAD_W(kbase);
    DWRITE_W(Ws0);
    __syncthreads();

    const int NT = (F / 2) / DBK;  // 43 (odd)
    for (int t = 0; t < NT - 1; t += 2) {
        DSTAGE_A(As1, kbase + (t + 1) * DBK);
        DLOAD_W(kbase + (t + 1) * DBK);
        DCOMPUTE(As0, Ws0);
        DWRITE_W(Ws1);
        __syncthreads();
        if (t + 2 < NT) {
            DSTAGE_A(As0, kbase + (t + 2) * DBK);
            DLOAD_W(kbase + (t + 2) * DBK);
        }
        DCOMPUTE(As1, Ws1);
        if (t + 2 < NT) DWRITE_W(Ws0);
        __syncthreads();
    }
    DCOMPUTE(As0, Ws0);  // final step 42 (staged in last loop iteration)

#undef DSTAGE_A
#undef DLOAD_W
#undef DWRITE_W
#undef DCOMPUTE

#pragma unroll
    for (int i = 0; i < 4; ++i) {
        const int ml = wr * 64 + i * 16 + quad * 4;
#pragma unroll
        for (int r = 0; r < 4; ++r) {
            const int lr = mt * BM + ml + r;
            if (lr < count) {
                const int t = row_t[rowbase + ml + r];
                float* orow = out + (size_t)t * H + h0;
#pragma unroll
                for (int j = 0; j < 4; ++j)
                    atomicAdd(&orow[wc * 64 + j * 16 + l16], acc[i][j][r]);
            }
        }
    }
}

extern "C" void kernel_launch(void* const* d_in, const int* in_sizes, int n_in,
                              void* d_out, int out_size, void* d_ws, size_t ws_size,
                              hipStream_t stream) {
    const float* x  = (const float*)d_in[0];
    const float* rw = (const float*)d_in[1];
    const float* gw = (const float*)d_in[2];
    const float* uw = (const float*)d_in[3];
    const float* dw = (const float*)d_in[4];
    float* out = (float*)d_out;
    char* ws = (char*)d_ws;

    int*   cnt    = (int*)(ws + 0);
    int*   off    = (int*)(ws + 256);
    int*   list_t = (int*)(ws + 1024);
    float* list_w = (float*)(ws + 1024 + 65536);
    int*   row_t  = (int*)(ws + 1024 + 2 * 65536);
    float* row_w  = (float*)(ws + 1024 + 2 * 65536 + ROWCAP * 4);
    __bf16* Abuf  = (__bf16*)(ws + 262144);
    __bf16* act   = (__bf16*)(ws + 262144 + (size_t)ROWCAP * H * 2);

    hipMemsetAsync(d_out, 0, (size_t)out_size * sizeof(float), stream);
    hipMemsetAsync(ws, 0, 1024, stream);

    router_kernel<<<T / 4, 256, 0, stream>>>(x, rw, cnt, list_t, list_w);
    offsets_kernel<<<1, 64, 0, stream>>>(cnt, off);
    gather_kernel<<<dim3(T, E), 256, 0, stream>>>(x, cnt, off, list_t, list_w, Abuf, row_t, row_w);
    gateup_kernel<<<dim3(F / BN, T / BM, E), 256, 0, stream>>>(Abuf, gw, uw, cnt, off, row_w, act);
    down_kernel<<<dim3(32, T / BM, E), 256, 0, stream>>>(act, dw, cnt, off, row_t, out);
}